// Round 1
// baseline (662.624 us; speedup 1.0000x reference)
//
#include <hip/hip_runtime.h>
#include <stdint.h>

// Fully-fused MLP: 1048576 x (64 -> 128 -> 128 -> 128 -> 128 -> 64)
// ReLU after all but last layer. fp32 in/out, bf16 MFMA compute (fp32 accum).
//
// Scheme: keep activations TRANSPOSED (features x rows). Each layer is
// H_next = relu(W * H + b), computed with mfma_f32_16x16x32_bf16:
//   A = W   (m = out_feature, k = in_feature)  -> 16B contiguous row loads
//   B = H   (k = in_feature,  n = batch row)
//   C/D: lane holds (m = quad*4+reg, n = lane&15)  [guide §3, m89-verified]
// C->B between layers via a wave-private LDS tile stored col-major
// (act[col][feature], LDF=136 pad): write = ds_write_b64, read = ds_read_b128.
// No cross-wave sharing -> no __syncthreads at all.

#define D_IN   64
#define D_HID  128
#define D_OUT  64
#define N_HID  3                    // hidden layers (DEPTH-1)
#define NT     4                    // 16-row batch tiles per wave
#define WAVES  2                    // waves per block
#define LDF    136                  // padded feature stride (bf16 elems)
#define ROWS_PER_WAVE  (NT * 16)    // 64
#define ROWS_PER_BLOCK (WAVES * ROWS_PER_WAVE)  // 128

typedef __attribute__((ext_vector_type(8))) short  short8;   // 8 x bf16 (4 VGPRs)
typedef __attribute__((ext_vector_type(4))) float  floatx4;  // MFMA C/D

__device__ __forceinline__ unsigned int bfround(unsigned int u) {
  // round-to-nearest-even fp32 -> bf16 (top 16 bits)
  return u + 0x7fffu + ((u >> 16) & 1u);
}
__device__ __forceinline__ unsigned int pack2bf(float lo, float hi) {
  unsigned int ulo = bfround(__float_as_uint(lo)) >> 16;
  unsigned int uhi = bfround(__float_as_uint(hi)) & 0xffff0000u;
  return ulo | uhi;
}

// LDS access via memcpy + assume_aligned: may-alias semantics (safe WAR/RAW
// ordering on the reused act buffer) while still emitting ds_read_b128 /
// ds_write_b64.
__device__ __forceinline__ short8 lds_load16(const unsigned short* p) {
  short8 v;
  __builtin_memcpy(&v, __builtin_assume_aligned(p, 16), 16);
  return v;
}
__device__ __forceinline__ void lds_store8(unsigned short* p, unsigned int lo, unsigned int hi) {
  unsigned int d[2] = {lo, hi};
  __builtin_memcpy(__builtin_assume_aligned(p, 8), d, 8);
}

__device__ __forceinline__ floatx4 mfma16(short8 a, short8 b, floatx4 c) {
  return __builtin_amdgcn_mfma_f32_16x16x32_bf16(a, b, c, 0, 0, 0);
}

// ---- tiny pre-pass: fp32 weights -> bf16 in workspace -------------------
#define W_IN_ELEMS  (D_HID * D_IN)                   // 8192
#define W_HID_ELEMS (N_HID * D_HID * D_HID)          // 49152
#define W_OUT_ELEMS (D_OUT * D_HID)                  // 8192
#define W_TOTAL     (W_IN_ELEMS + W_HID_ELEMS + W_OUT_ELEMS)  // 65536

__global__ void wconvert_kernel(const float* __restrict__ w_in,
                                const float* __restrict__ w_hid,
                                const float* __restrict__ w_out,
                                unsigned short* __restrict__ wbf) {
  const int i = blockIdx.x * 256 + threadIdx.x;
  float v;
  if (i < W_IN_ELEMS)                    v = w_in[i];
  else if (i < W_IN_ELEMS + W_HID_ELEMS) v = w_hid[i - W_IN_ELEMS];
  else                                   v = w_out[i - W_IN_ELEMS - W_HID_ELEMS];
  wbf[i] = (unsigned short)(bfround(__float_as_uint(v)) >> 16);
}

// ---- main fused kernel ---------------------------------------------------
__global__ __launch_bounds__(WAVES * 64, 2) void mlp_kernel(
    const float* __restrict__ x,
    const unsigned short* __restrict__ wbf,
    const float* __restrict__ b_in,
    const float* __restrict__ b_hid,
    const float* __restrict__ b_out,
    float* __restrict__ out) {
  // wave-private activation scratch: [wave][nt][col(16) x feature(LDF)]
  __shared__ __align__(16) unsigned short act_s[WAVES][NT][16 * LDF];
  static_assert(sizeof(act_s) == WAVES * NT * 16 * LDF * 2, "lds");

  const int wv   = threadIdx.x >> 6;
  const int lane = threadIdx.x & 63;
  const int q    = lane >> 4;    // quad 0..3
  const int c    = lane & 15;    // batch col within tile / A-operand row

  const int rowbase = (blockIdx.x * WAVES + wv) * ROWS_PER_WAVE;

  unsigned short* act = &act_s[wv][0][0];
  // per-thread bases into the act tile
  unsigned short* act_w = act + c * LDF + q * 4;        // write base (m side)
  const unsigned short* act_r = act + c * LDF + q * 8;  // read base (k side)

  const unsigned short* w0 = wbf;                        // [128][64]
  const unsigned short* wh = wbf + W_IN_ELEMS;           // [3][128][128]
  const unsigned short* wo = wbf + W_IN_ELEMS + W_HID_ELEMS;  // [64][128]

  short8 bfrag[NT][4];

  // ---- layer 0: build B-frags straight from x (K = 64 -> 2 ksteps) ----
#pragma unroll
  for (int nt = 0; nt < NT; ++nt) {
    const float* xr = x + (rowbase + nt * 16 + c) * D_IN + q * 8;
#pragma unroll
    for (int s = 0; s < 2; ++s) {
      floatx4 f0 = *(const floatx4*)(xr + s * 32);
      floatx4 f1 = *(const floatx4*)(xr + s * 32 + 4);
      union { short8 s8; unsigned int u[4]; } ub;
      ub.u[0] = pack2bf(f0[0], f0[1]);
      ub.u[1] = pack2bf(f0[2], f0[3]);
      ub.u[2] = pack2bf(f1[0], f1[1]);
      ub.u[3] = pack2bf(f1[2], f1[3]);
      bfrag[nt][s] = ub.s8;
    }
  }

  // ---- layer 0 compute: M=128 (8 mtiles), K=64, ReLU -> act ----
#pragma unroll
  for (int mt = 0; mt < 8; ++mt) {
    const unsigned short* wr = w0 + (mt * 16 + c) * D_IN + q * 8;
    short8 a0 = *(const short8*)(wr);
    short8 a1 = *(const short8*)(wr + 32);
    floatx4 bias = *(const floatx4*)(b_in + mt * 16 + q * 4);
#pragma unroll
    for (int nt = 0; nt < NT; ++nt) {
      floatx4 acc = bias;
      acc = mfma16(a0, bfrag[nt][0], acc);
      acc = mfma16(a1, bfrag[nt][1], acc);
      lds_store8(act_w + nt * (16 * LDF) + mt * 16,
                 pack2bf(fmaxf(acc[0], 0.f), fmaxf(acc[1], 0.f)),
                 pack2bf(fmaxf(acc[2], 0.f), fmaxf(acc[3], 0.f)));
    }
  }

  // ---- hidden layers: M=128, K=128 (4 ksteps), ReLU -> act ----
  for (int l = 0; l < N_HID; ++l) {
#pragma unroll
    for (int nt = 0; nt < NT; ++nt) {
#pragma unroll
      for (int s = 0; s < 4; ++s)
        bfrag[nt][s] = lds_load16(act_r + nt * (16 * LDF) + s * 32);
    }
    const unsigned short* wl = wh + l * (D_HID * D_HID);
    const float* bl = b_hid + l * D_HID;
#pragma unroll
    for (int mt = 0; mt < 8; ++mt) {
      const unsigned short* wr = wl + (mt * 16 + c) * D_HID + q * 8;
      short8 a0 = *(const short8*)(wr);
      short8 a1 = *(const short8*)(wr + 32);
      short8 a2 = *(const short8*)(wr + 64);
      short8 a3 = *(const short8*)(wr + 96);
      floatx4 bias = *(const floatx4*)(bl + mt * 16 + q * 4);
#pragma unroll
      for (int nt = 0; nt < NT; ++nt) {
        floatx4 acc = bias;
        acc = mfma16(a0, bfrag[nt][0], acc);
        acc = mfma16(a1, bfrag[nt][1], acc);
        acc = mfma16(a2, bfrag[nt][2], acc);
        acc = mfma16(a3, bfrag[nt][3], acc);
        lds_store8(act_w + nt * (16 * LDF) + mt * 16,
                   pack2bf(fmaxf(acc[0], 0.f), fmaxf(acc[1], 0.f)),
                   pack2bf(fmaxf(acc[2], 0.f), fmaxf(acc[3], 0.f)));
      }
    }
  }

  // ---- output layer: M=64 (4 mtiles), K=128, no activation ----
#pragma unroll
  for (int nt = 0; nt < NT; ++nt) {
#pragma unroll
    for (int s = 0; s < 4; ++s)
      bfrag[nt][s] = lds_load16(act_r + nt * (16 * LDF) + s * 32);
  }
#pragma unroll
  for (int mt = 0; mt < 4; ++mt) {
    const unsigned short* wr = wo + (mt * 16 + c) * D_HID + q * 8;
    short8 a0 = *(const short8*)(wr);
    short8 a1 = *(const short8*)(wr + 32);
    short8 a2 = *(const short8*)(wr + 64);
    short8 a3 = *(const short8*)(wr + 96);
    floatx4 bias = *(const floatx4*)(b_out + mt * 16 + q * 4);
#pragma unroll
    for (int nt = 0; nt < NT; ++nt) {
      floatx4 acc = bias;
      acc = mfma16(a0, bfrag[nt][0], acc);
      acc = mfma16(a1, bfrag[nt][1], acc);
      acc = mfma16(a2, bfrag[nt][2], acc);
      acc = mfma16(a3, bfrag[nt][3], acc);
      // lane holds out[row = rowbase+nt*16+c][feat = mt*16 + q*4 + reg]
      *(floatx4*)(out + (rowbase + nt * 16 + c) * D_OUT + mt * 16 + q * 4) = acc;
    }
  }
}

extern "C" void kernel_launch(void* const* d_in, const int* in_sizes, int n_in,
                              void* d_out, int out_size, void* d_ws, size_t ws_size,
                              hipStream_t stream) {
  const float* x     = (const float*)d_in[0];
  const float* w_in  = (const float*)d_in[1];
  const float* b_in  = (const float*)d_in[2];
  const float* w_hid = (const float*)d_in[3];
  const float* b_hid = (const float*)d_in[4];
  const float* w_out = (const float*)d_in[5];
  const float* b_out = (const float*)d_in[6];
  float* out = (float*)d_out;
  unsigned short* wbf = (unsigned short*)d_ws;  // 131072 bytes used

  // weights fp32 -> bf16 (re-done every launch; ws is re-poisoned)
  wconvert_kernel<<<W_TOTAL / 256, 256, 0, stream>>>(w_in, w_hid, w_out, wbf);

  const int N = in_sizes[0] / D_IN;            // 1048576
  const int blocks = N / ROWS_PER_BLOCK;       // 8192
  mlp_kernel<<<blocks, WAVES * 64, 0, stream>>>(x, wbf, b_in, b_hid, b_out, out);
}